// Round 3
// baseline (4834.457 us; speedup 1.0000x reference)
//
#include <hip/hip_runtime.h>
#include <hip/hip_cooperative_groups.h>

namespace cg = cooperative_groups;

#define B 128
#define S 16
#define E 512
#define R 1000
#define K3 1536
#define NW0 1920   // init worklist: 128 b * 15 pairs
#define NWS 256    // per-step worklist: 128 b * 2 entries
#define SCALE 0.04419417382415922f
#define NBLK 256   // cooperative grid size (1 block/CU guaranteed resident)

static __device__ __forceinline__ float sigm(float x) { return 1.f / (1.f + expf(-x)); }

// ---------- block reductions (256 threads) ----------
static __device__ __forceinline__ float brsum(float v, float* sb) {
  int tid = threadIdx.x;
  sb[tid] = v; __syncthreads();
  for (int s = 128; s > 0; s >>= 1) {
    if (tid < s) sb[tid] += sb[tid + s];
    __syncthreads();
  }
  float r = sb[0]; __syncthreads();
  return r;
}
static __device__ __forceinline__ float brmax(float v, float* sb) {
  int tid = threadIdx.x;
  sb[tid] = v; __syncthreads();
  for (int s = 128; s > 0; s >>= 1) {
    if (tid < s) sb[tid] = fmaxf(sb[tid], sb[tid + s]);
    __syncthreads();
  }
  float r = sb[0]; __syncthreads();
  return r;
}

#define TILE_FMA_OFF(ACC, OFF) \
  _Pragma("unroll") \
  for (int k = 0; k < 16; ++k) { \
    float4 a4 = *(const float4*)&As[k][(OFF) + ty * 4]; \
    float4 w4 = *(const float4*)&Ws[k][tx * 4]; \
    ACC[0][0] = fmaf(a4.x, w4.x, ACC[0][0]); ACC[0][1] = fmaf(a4.x, w4.y, ACC[0][1]); \
    ACC[0][2] = fmaf(a4.x, w4.z, ACC[0][2]); ACC[0][3] = fmaf(a4.x, w4.w, ACC[0][3]); \
    ACC[1][0] = fmaf(a4.y, w4.x, ACC[1][0]); ACC[1][1] = fmaf(a4.y, w4.y, ACC[1][1]); \
    ACC[1][2] = fmaf(a4.y, w4.z, ACC[1][2]); ACC[1][3] = fmaf(a4.y, w4.w, ACC[1][3]); \
    ACC[2][0] = fmaf(a4.z, w4.x, ACC[2][0]); ACC[2][1] = fmaf(a4.z, w4.y, ACC[2][1]); \
    ACC[2][2] = fmaf(a4.z, w4.z, ACC[2][2]); ACC[2][3] = fmaf(a4.z, w4.w, ACC[2][3]); \
    ACC[3][0] = fmaf(a4.w, w4.x, ACC[3][0]); ACC[3][1] = fmaf(a4.w, w4.y, ACC[3][1]); \
    ACC[3][2] = fmaf(a4.w, w4.z, ACC[3][2]); ACC[3][3] = fmaf(a4.w, w4.w, ACC[3][3]); \
  }

// ---------- init: pos identity + full worklist ----------
__global__ __launch_bounds__(256) void k_initwl(int* __restrict__ pos,
                                                int* __restrict__ wlb,
                                                int* __restrict__ wlL,
                                                int* __restrict__ wlR) {
  int idx = blockIdx.x * 256 + threadIdx.x;
  if (idx < B * 16) pos[idx] = idx & 15;
  if (idx < NW0) {
    wlb[idx] = idx / 15;
    int i = idx % 15;
    wlL[idx] = i;
    wlR[idx] = i + 1;
  }
}

// ---------- 64x64 LDS transpose: dst[c*ldd + r] = src[r*Cc + c] ----------
__global__ __launch_bounds__(256) void k_tr(const float* __restrict__ src, int Cc,
                                            float* __restrict__ dst, int ldd) {
  __shared__ float t[64][65];
  int tid = threadIdx.x, tx = tid & 15, ty = tid >> 4;
  int rb = blockIdx.y * 64, cb = blockIdx.x * 64;
#pragma unroll
  for (int i = 0; i < 4; ++i) {
    int r = rb + ty + i * 16;
    float4 v = *(const float4*)(src + (size_t)r * Cc + cb + tx * 4);
    t[ty + i * 16][tx * 4 + 0] = v.x; t[ty + i * 16][tx * 4 + 1] = v.y;
    t[ty + i * 16][tx * 4 + 2] = v.z; t[ty + i * 16][tx * 4 + 3] = v.w;
  }
  __syncthreads();
#pragma unroll
  for (int i = 0; i < 4; ++i) {
    int c = cb + ty + i * 16;
    float4 v;
    v.x = t[tx * 4 + 0][ty + i * 16]; v.y = t[tx * 4 + 1][ty + i * 16];
    v.z = t[tx * 4 + 2][ty + i * 16]; v.w = t[tx * 4 + 3][ty + i * 16];
    *(float4*)(dst + (size_t)c * ldd + rb + tx * 4) = v;
  }
}

// ---------- generic tiled gemm (setup only) ----------
__global__ __launch_bounds__(256) void k_gemm(const float* __restrict__ A, int lda, int M,
                                              const float* __restrict__ W, int N, int K,
                                              const float* __restrict__ bias, float scale,
                                              float* __restrict__ C, int ldc) {
  __shared__ float As[16][64];
  __shared__ float Ws[16][64];
  int tid = threadIdx.x;
  int mBase = blockIdx.y * 64;
  int nBase = blockIdx.x * 64;
  int tx = tid & 15, ty = tid >> 4;
  int li = tid & 63;
  int lk = (tid >> 6) * 4;
  float acc[4][4] = {{0.f,0.f,0.f,0.f},{0.f,0.f,0.f,0.f},{0.f,0.f,0.f,0.f},{0.f,0.f,0.f,0.f}};
  int m = mBase + li;
  const float* Arow = (m < M) ? (A + (size_t)m * lda) : nullptr;
  int n = nBase + li;
  const float* Wrow = (n < N) ? (W + (size_t)n * K) : nullptr;

  float4 av = Arow ? *(const float4*)(Arow + lk) : make_float4(0.f, 0.f, 0.f, 0.f);
  float4 wv = Wrow ? *(const float4*)(Wrow + lk) : make_float4(0.f, 0.f, 0.f, 0.f);

  for (int k0 = 0; k0 < K; k0 += 16) {
    As[lk + 0][li] = av.x; As[lk + 1][li] = av.y;
    As[lk + 2][li] = av.z; As[lk + 3][li] = av.w;
    Ws[lk + 0][li] = wv.x; Ws[lk + 1][li] = wv.y;
    Ws[lk + 2][li] = wv.z; Ws[lk + 3][li] = wv.w;
    __syncthreads();
    if (k0 + 16 < K) {
      av = Arow ? *(const float4*)(Arow + k0 + 16 + lk) : make_float4(0.f, 0.f, 0.f, 0.f);
      wv = Wrow ? *(const float4*)(Wrow + k0 + 16 + lk) : make_float4(0.f, 0.f, 0.f, 0.f);
    }
    TILE_FMA_OFF(acc, 0)
    __syncthreads();
  }
#pragma unroll
  for (int r = 0; r < 4; ++r) {
    int mm = mBase + ty * 4 + r;
    if (mm >= M) continue;
#pragma unroll
    for (int c = 0; c < 4; ++c) {
      int nn = nBase + tx * 4 + c;
      if (nn >= N) continue;
      float v = acc[r][c] * scale;
      if (bias) v += bias[nn];
      C[(size_t)mm * ldc + nn] = v;
    }
  }
}

// ---------- setup misc: zero Wbig pad rows, v12, c0, gb ----------
__global__ __launch_bounds__(256) void k_misc(float* __restrict__ Wbig,
                                              const float* __restrict__ WqT,
                                              const float* __restrict__ WkT,
                                              const float* __restrict__ bq,
                                              const float* __restrict__ bk,
                                              const float* __restrict__ KREL,
                                              float* __restrict__ v12,
                                              float* __restrict__ c0s,
                                              float* __restrict__ gb) {
  __shared__ float sb[256];
  int blk = blockIdx.x, tid = threadIdx.x;
  if (blk < 24) {
    for (int n = tid; n < K3; n += 256) Wbig[(size_t)(1000 + blk) * K3 + n] = 0.f;
  } else if (blk < 26) {
    int i = (blk - 24) * 256 + tid;
    const float* wq = WqT + (size_t)i * E;
    const float* wk = WkT + (size_t)i * E;
    float s = 0.f;
    for (int e = 0; e < E; ++e) s += wq[e] * bk[e] + bq[e] * wk[e];
    v12[i] = s;
  } else if (blk == 26) {
    float p = 0.f;
    for (int e = tid; e < E; e += 256) p += bq[e] * bk[e];
    float s = brsum(p, sb);
    if (tid == 0) c0s[0] = s;
  } else if (blk >= 28) {
    int r = (blk - 28) * 256 + tid;
    if (r < R) {
      const float* kr = KREL + (size_t)r * E;
      float s = 0.f;
      for (int e = 0; e < E; ++e) s += bq[e] * kr[e];
      gb[r] = s;
    }
  }
}

// ---------- GI init: GI[row] = EW[token[row]] + b_ih ----------
__global__ __launch_bounds__(256) void k_giinit(const int* __restrict__ tokens,
                                                const float* __restrict__ Wbig,
                                                const float* __restrict__ bih,
                                                float* __restrict__ GI) {
  int row = blockIdx.x;
  int tok = tokens[row];
  const float4* src = (const float4*)(Wbig + (size_t)tok * K3);
  const float4* bv = (const float4*)bih;
  float4* dst = (float4*)(GI + (size_t)row * K3);
  for (int i = threadIdx.x; i < K3 / 4; i += 256) {
    float4 a = src[i], b = bv[i];
    dst[i] = make_float4(a.x + b.x, a.y + b.y, a.z + b.z, a.w + b.w);
  }
}

// ================= cooperative mega-kernel =================
struct MegaArgs {
  const float* Gbig; const float* gb; const float* v12; const float* c0s;
  const float* Whh; const float* bhh; const float* bih;
  const float* wfc; const float* bfc; const float* Wbig;
  float* GI; float* GHC; float* H1C; float* PAIR; float* SCT; float* A2;
  float* SC; float* LOSS; float* SCR;
  int* pos0; int* pos1; int* wlb; int* wlL; int* wlR; int* xdst;
  float* out;
};

// h1 for worklist entry w -> H1C[w]
static __device__ void dev_h1(int tid, int w, const int* wlb, const int* wlL,
                              const float* GI, const float* bhh, float* H1C) {
  int b = wlb[w], ls = wlL[w];
  const float* gi = GI + (size_t)(b * 16 + ls) * K3;
  float* h = H1C + (size_t)w * E;
  for (int e = tid; e < E; e += 256) {
    float r = sigm(gi[e] + bhh[e]);
    float z = sigm(gi[E + e] + bhh[E + e]);
    h[e] = (1.f - z) * tanhf(gi[2 * E + e] + r * bhh[2 * E + e]);
  }
}

// GHC tile: C[m,n] = H1C[m,:] . Whh[n,:] + bhh[n]
static __device__ void dev_ghc_tile(int tid, float (*As)[128], float (*Ws)[64],
                                    int nBase, int mBase, const float* H1C, int M,
                                    const float* Whh, const float* bhh, float* GHC) {
  int tx = tid & 15, ty = tid >> 4;
  int li = tid & 63, lk = (tid >> 6) * 4;
  float acc[4][4] = {{0.f,0.f,0.f,0.f},{0.f,0.f,0.f,0.f},{0.f,0.f,0.f,0.f},{0.f,0.f,0.f,0.f}};
  int m = mBase + li;
  const float* Arow = (m < M) ? (H1C + (size_t)m * E) : nullptr;
  const float* Wrow = Whh + (size_t)(nBase + li) * E;
  float4 av = Arow ? *(const float4*)(Arow + lk) : make_float4(0.f, 0.f, 0.f, 0.f);
  float4 wv = *(const float4*)(Wrow + lk);
  for (int k0 = 0; k0 < E; k0 += 16) {
    As[lk + 0][li] = av.x; As[lk + 1][li] = av.y;
    As[lk + 2][li] = av.z; As[lk + 3][li] = av.w;
    Ws[lk + 0][li] = wv.x; Ws[lk + 1][li] = wv.y;
    Ws[lk + 2][li] = wv.z; Ws[lk + 3][li] = wv.w;
    __syncthreads();
    if (k0 + 16 < E) {
      av = Arow ? *(const float4*)(Arow + k0 + 16 + lk) : make_float4(0.f, 0.f, 0.f, 0.f);
      wv = *(const float4*)(Wrow + k0 + 16 + lk);
    }
    TILE_FMA_OFF(acc, 0)
    __syncthreads();
  }
#pragma unroll
  for (int r = 0; r < 4; ++r) {
    int mm = mBase + ty * 4 + r;
    if (mm >= M) continue;
#pragma unroll
    for (int c = 0; c < 4; ++c) {
      int nn = nBase + tx * 4 + c;
      GHC[(size_t)mm * K3 + nn] = acc[r][c] + bhh[nn];
    }
  }
}

// pair + fc score for worklist entry w (h1 from H1C)
static __device__ void dev_pairc(int tid, int w, const int* wlb, const int* wlL,
                                 const int* wlR, const float* GI, const float* GHC,
                                 const float* H1C, const float* wfc, const float* bfc,
                                 float* PAIR, float* SCR, float* sb) {
  int b = wlb[w], ls = wlL[w], rs = wlR[w];
  const float* gr = GI + (size_t)(b * 16 + rs) * K3;
  const float* gh = GHC + (size_t)w * K3;
  const float* h = H1C + (size_t)w * E;
  float* p = PAIR + (size_t)(b * 16 + ls) * E;
  float part = 0.f;
  for (int e = tid; e < E; e += 256) {
    float r = sigm(gr[e] + gh[e]);
    float z = sigm(gr[E + e] + gh[E + e]);
    float n = tanhf(gr[2 * E + e] + r * gh[2 * E + e]);
    float pv = (1.f - z) * n + z * h[e];
    p[e] = pv;
    part += pv * wfc[e];
  }
  float d = brsum(part, sb);
  if (tid == 0) SCR[b * 16 + ls] = sigm(d + bfc[0]);
}

// argmax + pos/worklist update (thread 0 of block b)
static __device__ void dev_sel(int b, int P, const float* SCR, const int* pin,
                               int* pout, int* wlb, int* wlL, int* wlR, int* xdst) {
  int L = P + 1;
  int lp[16];
  for (int i = 0; i < L; ++i) lp[i] = pin[b * 16 + i];
  float best = -1e30f; int sel = 0;
  for (int i = 0; i < P; ++i) {
    float v = SCR[b * 16 + lp[i]];
    if (v > best) { best = v; sel = i; }
  }
  int r1i = (sel + 2 < L) ? sel + 2 : L - 1;
  int l1 = lp[sel], r1 = lp[r1i];
  int l0 = (sel > 0) ? lp[sel - 1] : l1;
  int r0 = (sel > 0) ? lp[sel] : r1;
  wlb[2 * b] = b;     wlL[2 * b] = l0;     wlR[2 * b] = r0;
  wlb[2 * b + 1] = b; wlL[2 * b + 1] = l1; wlR[2 * b + 1] = r1;
  xdst[b] = b * 16 + l1;
  for (int i = 0; i < L - 1; ++i)
    pout[b * 16 + i] = (i <= sel) ? lp[i] : lp[i + 1];
}

// qsc tile: SCT[m, n] from PAIR[xdst[m]] . Gbig[n]
static __device__ void dev_qsc_tile(int tid, float (*As)[128], float (*Ws)[64],
                                    int nBase, int mBase, const float* PAIR,
                                    const int* xdst, const float* Gbig,
                                    const float* gb, float* SCT) {
  int tx = tid & 15, ty = tid >> 4;
  int li = tid & 63, lk = (tid >> 6) * 4;
  float acc[4][4] = {{0.f,0.f,0.f,0.f},{0.f,0.f,0.f,0.f},{0.f,0.f,0.f,0.f},{0.f,0.f,0.f,0.f}};
  const float* Arow = PAIR + (size_t)xdst[mBase + li] * E;
  int n = nBase + li;
  const float* Wrow = (n < 1512) ? (Gbig + (size_t)n * E) : nullptr;
  float4 av = *(const float4*)(Arow + lk);
  float4 wv = Wrow ? *(const float4*)(Wrow + lk) : make_float4(0.f, 0.f, 0.f, 0.f);
  for (int k0 = 0; k0 < E; k0 += 16) {
    As[lk + 0][li] = av.x; As[lk + 1][li] = av.y;
    As[lk + 2][li] = av.z; As[lk + 3][li] = av.w;
    Ws[lk + 0][li] = wv.x; Ws[lk + 1][li] = wv.y;
    Ws[lk + 2][li] = wv.z; Ws[lk + 3][li] = wv.w;
    __syncthreads();
    if (k0 + 16 < E) {
      av = *(const float4*)(Arow + k0 + 16 + lk);
      wv = Wrow ? *(const float4*)(Wrow + k0 + 16 + lk) : make_float4(0.f, 0.f, 0.f, 0.f);
    }
    TILE_FMA_OFF(acc, 0)
    __syncthreads();
  }
#pragma unroll
  for (int r = 0; r < 4; ++r) {
    int mm = mBase + ty * 4 + r;
#pragma unroll
    for (int c = 0; c < 4; ++c) {
      int nn = nBase + tx * 4 + c;
      if (nn >= 1512) continue;
      float v = (nn < 1000) ? (acc[r][c] + gb[nn]) * SCALE : acc[r][c];
      SCT[(size_t)mm * K3 + nn] = v;
    }
  }
}

// softmax/entropy + A2 build + GI row init (mode 0) / SC write (mode 1)
static __device__ void dev_sm(int tid, int b, int t, int mode, const float* SCT,
                              const float* PAIR, const int* xdst, const float* v12,
                              const float* c0s, float* SC, float* A2, float* GI,
                              const float* bih, float* LOSS, float* sb, float* sps) {
  const float* row = SCT + (size_t)b * K3;
  int xr = xdst[b];
  const float* sp = PAIR + (size_t)xr * E;
  for (int i = tid; i < E; i += 256) sps[i] = sp[i];
  __syncthreads();
  float part = 0.f;
  for (int i = tid; i < E; i += 256) part += sps[i] * (row[1000 + i] + v12[i]);
  float last = (brsum(part, sb) + c0s[0]) * SCALE;
  float s[4];
  float ml = last;
#pragma unroll
  for (int q = 0; q < 4; ++q) {
    int j = tid + q * 256;
    float v = (j < 1000) ? row[j] : -1e30f;
    s[q] = v;
    ml = fmaxf(ml, v);
  }
  float mx = brmax(ml, sb);
  float zp = 0.f, s1p = 0.f;
#pragma unroll
  for (int q = 0; q < 4; ++q) {
    int j = tid + q * 256;
    if (j < 1000) { float e = expf(s[q] - mx); zp += e; s1p += e * s[q]; }
  }
  if (tid == 0) { float e = expf(last - mx); zp += e; s1p += e * last; }
  float z = brsum(zp, sb);
  float s1 = brsum(s1p, sb);
  if (tid == 0) LOSS[b * 16 + t] = mx + logf(z) - s1 / z;
  if (mode == 0) {
    float inv = 1.f / z;
    float* a = A2 + (size_t)b * K3;
#pragma unroll
    for (int q = 0; q < 4; ++q) {
      int j = tid + q * 256;
      if (j < 1000) a[j] = expf(s[q] - mx) * inv;
    }
    if (tid < 24) a[1000 + tid] = 0.f;
    float pr = expf(last - mx) * inv;
    for (int i = tid; i < E; i += 256) a[1024 + i] = pr * sps[i];
    float* g = GI + (size_t)xr * K3;
    for (int n2 = tid; n2 < K3; n2 += 256) g[n2] = bih[n2];
  } else {
    float* so = SC + (size_t)b * (R + 1);
#pragma unroll
    for (int q = 0; q < 4; ++q) {
      int j = tid + q * 256;
      if (j < 1000) so[j] = s[q];
    }
    if (tid == 0) so[R] = last;
  }
}

// giup tile (both m-halves fused): GI[xdst[m], n] += A2[m, kslice] . Wbig[kslice, n]
static __device__ void dev_giup_tile(int tid, float (*As)[128], float (*Ws)[64],
                                     int nBase, int kz, const float* A2,
                                     const float* Wbig, float* GI, const int* xdst) {
  int tx = tid & 15, ty = tid >> 4;
  int liA = tid & 127, lkA = (tid >> 7) * 8;
  int liW = tid & 63, wr = tid >> 6;
  int kbeg = kz * 384;
  float acc0[4][4] = {{0.f,0.f,0.f,0.f},{0.f,0.f,0.f,0.f},{0.f,0.f,0.f,0.f},{0.f,0.f,0.f,0.f}};
  float acc1[4][4] = {{0.f,0.f,0.f,0.f},{0.f,0.f,0.f,0.f},{0.f,0.f,0.f,0.f},{0.f,0.f,0.f,0.f}};
  const float* Arow = A2 + (size_t)liA * K3;
  for (int k0 = kbeg; k0 < kbeg + 384; k0 += 16) {
    float4 a0 = *(const float4*)(Arow + k0 + lkA);
    float4 a1 = *(const float4*)(Arow + k0 + lkA + 4);
    As[lkA + 0][liA] = a0.x; As[lkA + 1][liA] = a0.y;
    As[lkA + 2][liA] = a0.z; As[lkA + 3][liA] = a0.w;
    As[lkA + 4][liA] = a1.x; As[lkA + 5][liA] = a1.y;
    As[lkA + 6][liA] = a1.z; As[lkA + 7][liA] = a1.w;
#pragma unroll
    for (int j = 0; j < 4; ++j)
      Ws[wr * 4 + j][liW] = Wbig[(size_t)(k0 + wr * 4 + j) * K3 + nBase + liW];
    __syncthreads();
    TILE_FMA_OFF(acc0, 0)
    TILE_FMA_OFF(acc1, 64)
    __syncthreads();
  }
#pragma unroll
  for (int r = 0; r < 4; ++r) {
    size_t crow0 = (size_t)xdst[ty * 4 + r] * K3;
    size_t crow1 = (size_t)xdst[64 + ty * 4 + r] * K3;
#pragma unroll
    for (int c = 0; c < 4; ++c) {
      int nn = nBase + tx * 4 + c;
      atomicAdd(&GI[crow0 + nn], acc0[r][c]);
      atomicAdd(&GI[crow1 + nn], acc1[r][c]);
    }
  }
}

__global__ __launch_bounds__(256) void k_mega(MegaArgs a) {
  cg::grid_group grid = cg::this_grid();
  __shared__ float As[16][128];
  __shared__ float Ws[16][64];
  __shared__ float sb[256];
  __shared__ float sps[E];
  int blk = blockIdx.x, tid = threadIdx.x;

  // ---- setup inside coop: h1 for NW0, GHC gemm (24x30 tiles), pairc NW0 ----
  for (int w = blk; w < NW0; w += NBLK)
    dev_h1(tid, w, a.wlb, a.wlL, a.GI, a.bhh, a.H1C);
  grid.sync();
  for (int ti = blk; ti < 24 * 30; ti += NBLK)
    dev_ghc_tile(tid, As, Ws, (ti % 24) * 64, (ti / 24) * 64, a.H1C, NW0,
                 a.Whh, a.bhh, a.GHC);
  grid.sync();
  for (int w = blk; w < NW0; w += NBLK)
    dev_pairc(tid, w, a.wlb, a.wlL, a.wlR, a.GI, a.GHC, a.H1C, a.wfc, a.bfc,
              a.PAIR, a.SCR, sb);
  grid.sync();

  // ---- 14 merge steps ----
  for (int t = 0; t < 14; ++t) {
    const int* pin = (t & 1) ? a.pos1 : a.pos0;
    int* pout = (t & 1) ? a.pos0 : a.pos1;
    if (blk < B && tid == 0)
      dev_sel(blk, 15 - t, a.SCR, pin, pout, a.wlb, a.wlL, a.wlR, a.xdst);
    grid.sync();
    if (blk < 48)
      dev_qsc_tile(tid, As, Ws, (blk % 24) * 64, (blk / 24) * 64, a.PAIR,
                   a.xdst, a.Gbig, a.gb, a.SCT);
    grid.sync();
    if (blk < B)
      dev_sm(tid, blk, t, 0, a.SCT, a.PAIR, a.xdst, a.v12, a.c0s, a.SC, a.A2,
             a.GI, a.bih, a.LOSS, sb, sps);
    grid.sync();
    if (blk < 96)
      dev_giup_tile(tid, As, Ws, (blk % 24) * 64, blk / 24, a.A2, a.Wbig,
                    a.GI, a.xdst);
    grid.sync();
    if (blk < NWS)
      dev_h1(tid, blk, a.wlb, a.wlL, a.GI, a.bhh, a.H1C);
    grid.sync();
    if (blk < 96)
      dev_ghc_tile(tid, As, Ws, (blk % 24) * 64, (blk / 24) * 64, a.H1C, NWS,
                   a.Whh, a.bhh, a.GHC);
    grid.sync();
    if (blk < NWS)
      dev_pairc(tid, blk, a.wlb, a.wlL, a.wlR, a.GI, a.GHC, a.H1C, a.wfc, a.bfc,
                a.PAIR, a.SCR, sb);
    grid.sync();
  }

  // ---- final: h2 = PAIR[b][pos[0]] (pos0 after 14 steps); attn + loss col 15 ----
  if (blk < B && tid == 0) a.xdst[blk] = blk * 16 + a.pos0[blk * 16];
  grid.sync();
  if (blk < 48)
    dev_qsc_tile(tid, As, Ws, (blk % 24) * 64, (blk / 24) * 64, a.PAIR,
                 a.xdst, a.Gbig, a.gb, a.SCT);
  grid.sync();
  if (blk < B)
    dev_sm(tid, blk, 15, 1, a.SCT, a.PAIR, a.xdst, a.v12, a.c0s, a.SC, a.A2,
           a.GI, a.bih, a.LOSS, sb, sps);
  grid.sync();
  const int NS = B * (R + 1);
  for (int idx = blk * 256 + tid; idx < NS + B * 16; idx += NBLK * 256) {
    if (idx < NS) {
      a.out[idx] = a.SC[idx];
    } else {
      int r = idx - NS;
      int tt = r & 15;
      a.out[idx] = (tt == 14) ? 0.f : a.LOSS[r];
    }
  }
}

extern "C" void kernel_launch(void* const* d_in, const int* in_sizes, int n_in,
                              void* d_out, int out_size, void* d_ws, size_t ws_size,
                              hipStream_t stream) {
  (void)in_sizes; (void)n_in; (void)out_size; (void)ws_size;
  const int* tokens = (const int*)d_in[0];
  const float* emb = (const float*)d_in[1];
  const float* W_ih = (const float*)d_in[2];
  const float* W_hh = (const float*)d_in[3];
  const float* b_ih = (const float*)d_in[4];
  const float* b_hh = (const float*)d_in[5];
  const float* w_fc = (const float*)d_in[6];
  const float* b_fc = (const float*)d_in[7];
  const float* Wq = (const float*)d_in[8];
  const float* bq = (const float*)d_in[9];
  const float* Wk = (const float*)d_in[10];
  const float* bk = (const float*)d_in[11];
  float* out = (float*)d_out;

  float* ws = (float*)d_ws;
  size_t o = 0;
  float* GI = ws + o;    o += (size_t)B * S * K3;
  float* GHC = ws + o;   o += (size_t)NW0 * K3;
  float* H1C = ws + o;   o += (size_t)NW0 * E;
  float* PAIR = ws + o;  o += (size_t)B * S * E;
  float* Wbig = ws + o;  o += (size_t)K3 * K3;       // [EW(1000) | 0(24) | W_ih^T(512)] k-major
  float* Gbig = ws + o;  o += (size_t)1512 * E;      // [G2(1000) ; Mqk(512)]
  float* KREL = ws + o;  o += (size_t)R * E;
  float* WqT = ws + o;   o += (size_t)E * E;
  float* WkT = ws + o;   o += (size_t)E * E;
  float* SCT = ws + o;   o += (size_t)B * K3;
  float* A2 = ws + o;    o += (size_t)B * K3;
  float* SC = ws + o;    o += (size_t)B * (R + 1);
  float* gb = ws + o;    o += 1024;
  float* v12 = ws + o;   o += 512;
  float* c0s = ws + o;   o += 16;
  float* LOSS = ws + o;  o += B * 16;
  float* SCR = ws + o;   o += B * 16;
  int* pos0 = (int*)(ws + o); o += B * 16;
  int* pos1 = (int*)(ws + o); o += B * 16;
  int* wlb = (int*)(ws + o);  o += NW0;
  int* wlL = (int*)(ws + o);  o += NW0;
  int* wlR = (int*)(ws + o);  o += NW0;
  int* xdst = (int*)(ws + o); o += B;

  // ---- setup (ordinary launches) ----
  k_initwl<<<8, 256, 0, stream>>>(pos0, wlb, wlL, wlR);
  k_tr<<<dim3(8, 8), 256, 0, stream>>>(Wq, E, WqT, E);
  k_tr<<<dim3(8, 8), 256, 0, stream>>>(Wk, E, WkT, E);
  k_tr<<<dim3(8, 24), 256, 0, stream>>>(W_ih, E, Wbig + (size_t)1024 * K3, K3);
  k_gemm<<<dim3(8, 16), 256, 0, stream>>>(emb, E, R, Wk, E, E, bk, 1.f, KREL, E);
  k_gemm<<<dim3(24, 16), 256, 0, stream>>>(emb, E, R, W_ih, K3, E, nullptr, 1.f, Wbig, K3);
  k_gemm<<<dim3(8, 16), 256, 0, stream>>>(KREL, E, R, WqT, E, E, nullptr, 1.f, Gbig, E);
  k_gemm<<<dim3(8, 8), 256, 0, stream>>>(WqT, E, E, WkT, E, E, nullptr, 1.f,
                                         Gbig + (size_t)1000 * E, E);
  k_misc<<<32, 256, 0, stream>>>(Wbig, WqT, WkT, bq, bk, KREL, v12, c0s, gb);
  k_giinit<<<B * S, 256, 0, stream>>>(tokens, Wbig, b_ih, GI);

  // ---- everything sequential in ONE cooperative kernel ----
  MegaArgs ma;
  ma.Gbig = Gbig; ma.gb = gb; ma.v12 = v12; ma.c0s = c0s;
  ma.Whh = W_hh; ma.bhh = b_hh; ma.bih = b_ih;
  ma.wfc = w_fc; ma.bfc = b_fc; ma.Wbig = Wbig;
  ma.GI = GI; ma.GHC = GHC; ma.H1C = H1C; ma.PAIR = PAIR; ma.SCT = SCT; ma.A2 = A2;
  ma.SC = SC; ma.LOSS = LOSS; ma.SCR = SCR;
  ma.pos0 = pos0; ma.pos1 = pos1; ma.wlb = wlb; ma.wlL = wlL; ma.wlR = wlR;
  ma.xdst = xdst;
  ma.out = out;
  void* kargs[] = { &ma };
  hipLaunchCooperativeKernel((void*)k_mega, dim3(NBLK), dim3(256), kargs, 0, stream);
}

// Round 5
// 1686.661 us; speedup vs baseline: 2.8663x; 2.8663x over previous
//
#include <hip/hip_runtime.h>

#define B 128
#define S 16
#define E 512
#define R 1000
#define K3 1536
#define NW0 1920   // init worklist: 128 b * 15 pairs
#define NWS 256    // per-step worklist: 128 b * 2 entries
#define SCALE 0.04419417382415922f

static __device__ __forceinline__ float sigm(float x) { return 1.f / (1.f + expf(-x)); }

// ---------- block reductions (256 threads) ----------
static __device__ __forceinline__ float brsum(float v, float* sb) {
  int tid = threadIdx.x;
  sb[tid] = v; __syncthreads();
  for (int s = 128; s > 0; s >>= 1) {
    if (tid < s) sb[tid] += sb[tid + s];
    __syncthreads();
  }
  float r = sb[0]; __syncthreads();
  return r;
}
static __device__ __forceinline__ float brmax(float v, float* sb) {
  int tid = threadIdx.x;
  sb[tid] = v; __syncthreads();
  for (int s = 128; s > 0; s >>= 1) {
    if (tid < s) sb[tid] = fmaxf(sb[tid], sb[tid + s]);
    __syncthreads();
  }
  float r = sb[0]; __syncthreads();
  return r;
}

#define TILE_FMA \
  _Pragma("unroll") \
  for (int k = 0; k < 16; ++k) { \
    float4 a4 = *(const float4*)&As[k][ty * 4]; \
    float4 w4 = *(const float4*)&Ws[k][tx * 4]; \
    acc[0][0] = fmaf(a4.x, w4.x, acc[0][0]); acc[0][1] = fmaf(a4.x, w4.y, acc[0][1]); \
    acc[0][2] = fmaf(a4.x, w4.z, acc[0][2]); acc[0][3] = fmaf(a4.x, w4.w, acc[0][3]); \
    acc[1][0] = fmaf(a4.y, w4.x, acc[1][0]); acc[1][1] = fmaf(a4.y, w4.y, acc[1][1]); \
    acc[1][2] = fmaf(a4.y, w4.z, acc[1][2]); acc[1][3] = fmaf(a4.y, w4.w, acc[1][3]); \
    acc[2][0] = fmaf(a4.z, w4.x, acc[2][0]); acc[2][1] = fmaf(a4.z, w4.y, acc[2][1]); \
    acc[2][2] = fmaf(a4.z, w4.z, acc[2][2]); acc[2][3] = fmaf(a4.z, w4.w, acc[2][3]); \
    acc[3][0] = fmaf(a4.w, w4.x, acc[3][0]); acc[3][1] = fmaf(a4.w, w4.y, acc[3][1]); \
    acc[3][2] = fmaf(a4.w, w4.z, acc[3][2]); acc[3][3] = fmaf(a4.w, w4.w, acc[3][3]); \
  }

// ---------- init: pos identity + full worklist ----------
__global__ __launch_bounds__(256) void k_initwl(int* __restrict__ pos,
                                                int* __restrict__ wlb,
                                                int* __restrict__ wlL,
                                                int* __restrict__ wlR) {
  int idx = blockIdx.x * 256 + threadIdx.x;
  if (idx < B * 16) pos[idx] = idx & 15;
  if (idx < NW0) {
    wlb[idx] = idx / 15;
    int i = idx % 15;
    wlL[idx] = i;
    wlR[idx] = i + 1;
  }
}

// ---------- 64x64 LDS transpose ----------
__global__ __launch_bounds__(256) void k_tr(const float* __restrict__ src, int Cc,
                                            float* __restrict__ dst, int ldd) {
  __shared__ float t[64][65];
  int tid = threadIdx.x, tx = tid & 15, ty = tid >> 4;
  int rb = blockIdx.y * 64, cb = blockIdx.x * 64;
#pragma unroll
  for (int i = 0; i < 4; ++i) {
    int r = rb + ty + i * 16;
    float4 v = *(const float4*)(src + (size_t)r * Cc + cb + tx * 4);
    t[ty + i * 16][tx * 4 + 0] = v.x; t[ty + i * 16][tx * 4 + 1] = v.y;
    t[ty + i * 16][tx * 4 + 2] = v.z; t[ty + i * 16][tx * 4 + 3] = v.w;
  }
  __syncthreads();
#pragma unroll
  for (int i = 0; i < 4; ++i) {
    int c = cb + ty + i * 16;
    float4 v;
    v.x = t[tx * 4 + 0][ty + i * 16]; v.y = t[tx * 4 + 1][ty + i * 16];
    v.z = t[tx * 4 + 2][ty + i * 16]; v.w = t[tx * 4 + 3][ty + i * 16];
    *(float4*)(dst + (size_t)c * ldd + rb + tx * 4) = v;
  }
}

// ---------- generic tiled gemm (register-prefetch): C = scale*A.W^T (+bias) ----------
__global__ __launch_bounds__(256) void k_gemm(const float* __restrict__ A, int lda, int M,
                                              const float* __restrict__ W, int N, int K,
                                              const float* __restrict__ bias, float scale,
                                              float* __restrict__ C, int ldc) {
  __shared__ float As[16][64];
  __shared__ float Ws[16][64];
  int tid = threadIdx.x;
  int mBase = blockIdx.y * 64;
  int nBase = blockIdx.x * 64;
  int tx = tid & 15, ty = tid >> 4;
  int li = tid & 63;
  int lk = (tid >> 6) * 4;
  float acc[4][4] = {{0.f,0.f,0.f,0.f},{0.f,0.f,0.f,0.f},{0.f,0.f,0.f,0.f},{0.f,0.f,0.f,0.f}};
  int m = mBase + li;
  const float* Arow = (m < M) ? (A + (size_t)m * lda) : nullptr;
  int n = nBase + li;
  const float* Wrow = (n < N) ? (W + (size_t)n * K) : nullptr;

  float4 av = Arow ? *(const float4*)(Arow + lk) : make_float4(0.f, 0.f, 0.f, 0.f);
  float4 wv = Wrow ? *(const float4*)(Wrow + lk) : make_float4(0.f, 0.f, 0.f, 0.f);

  for (int k0 = 0; k0 < K; k0 += 16) {
    As[lk + 0][li] = av.x; As[lk + 1][li] = av.y;
    As[lk + 2][li] = av.z; As[lk + 3][li] = av.w;
    Ws[lk + 0][li] = wv.x; Ws[lk + 1][li] = wv.y;
    Ws[lk + 2][li] = wv.z; Ws[lk + 3][li] = wv.w;
    __syncthreads();
    if (k0 + 16 < K) {
      av = Arow ? *(const float4*)(Arow + k0 + 16 + lk) : make_float4(0.f, 0.f, 0.f, 0.f);
      wv = Wrow ? *(const float4*)(Wrow + k0 + 16 + lk) : make_float4(0.f, 0.f, 0.f, 0.f);
    }
    TILE_FMA
    __syncthreads();
  }
#pragma unroll
  for (int r = 0; r < 4; ++r) {
    int mm = mBase + ty * 4 + r;
    if (mm >= M) continue;
#pragma unroll
    for (int c = 0; c < 4; ++c) {
      int nn = nBase + tx * 4 + c;
      if (nn >= N) continue;
      float v = acc[r][c] * scale;
      if (bias) v += bias[nn];
      C[(size_t)mm * ldc + nn] = v;
    }
  }
}

// ---------- setup misc: zero Wbig pad rows, v12, c0, gb ----------
__global__ __launch_bounds__(256) void k_misc(float* __restrict__ Wbig,
                                              const float* __restrict__ WqT,
                                              const float* __restrict__ WkT,
                                              const float* __restrict__ bq,
                                              const float* __restrict__ bk,
                                              const float* __restrict__ KREL,
                                              float* __restrict__ v12,
                                              float* __restrict__ c0s,
                                              float* __restrict__ gb) {
  __shared__ float sb[256];
  int blk = blockIdx.x, tid = threadIdx.x;
  if (blk < 24) {
    for (int n = tid; n < K3; n += 256) Wbig[(size_t)(1000 + blk) * K3 + n] = 0.f;
  } else if (blk < 26) {
    int i = (blk - 24) * 256 + tid;
    const float* wq = WqT + (size_t)i * E;
    const float* wk = WkT + (size_t)i * E;
    float s = 0.f;
    for (int e = 0; e < E; ++e) s += wq[e] * bk[e] + bq[e] * wk[e];
    v12[i] = s;
  } else if (blk == 26) {
    float p = 0.f;
    for (int e = tid; e < E; e += 256) p += bq[e] * bk[e];
    float s = brsum(p, sb);
    if (tid == 0) c0s[0] = s;
  } else if (blk >= 28) {
    int r = (blk - 28) * 256 + tid;
    if (r < R) {
      const float* kr = KREL + (size_t)r * E;
      float s = 0.f;
      for (int e = 0; e < E; ++e) s += bq[e] * kr[e];
      gb[r] = s;
    }
  }
}

// ---------- GI init gather + SCT pre-init (blocks >= B*S) ----------
__global__ __launch_bounds__(256) void k_giinit(const int* __restrict__ tokens,
                                                const float* __restrict__ Wbig,
                                                const float* __restrict__ bih,
                                                float* __restrict__ GI,
                                                const float* __restrict__ gb,
                                                float* __restrict__ SCT) {
  int row = blockIdx.x, tid = threadIdx.x;
  if (row < B * S) {
    int tok = tokens[row];
    const float4* src = (const float4*)(Wbig + (size_t)tok * K3);
    const float4* bv = (const float4*)bih;
    float4* dst = (float4*)(GI + (size_t)row * K3);
    for (int i = tid; i < K3 / 4; i += 256) {
      float4 a = src[i], b = bv[i];
      dst[i] = make_float4(a.x + b.x, a.y + b.y, a.z + b.z, a.w + b.w);
    }
  } else {
    int rb = row - B * S;  // 0..7 -> 16 SCT rows each
    for (int m = rb * 16; m < rb * 16 + 16; ++m) {
      float* r = SCT + (size_t)m * K3;
      for (int n = tid; n < 1512; n += 256) r[n] = (n < 1000) ? gb[n] : 0.f;
    }
  }
}

// ---------- h1 for worklist entries (+ optional GHC pre-init with bhh) ----------
__global__ __launch_bounds__(256) void k_h1c(const int* __restrict__ wlb,
                                             const int* __restrict__ wlL,
                                             const float* __restrict__ GI,
                                             const float* __restrict__ bhh,
                                             float* __restrict__ H1C,
                                             float* __restrict__ GHC) {
  int w = blockIdx.x, tid = threadIdx.x;
  const float* gi = GI + (size_t)(wlb[w] * 16 + wlL[w]) * K3;
  float* h = H1C + (size_t)w * E;
  for (int e = tid; e < E; e += 256) {
    float r = sigm(gi[e] + bhh[e]);
    float z = sigm(gi[E + e] + bhh[E + e]);
    h[e] = (1.f - z) * tanhf(gi[2 * E + e] + r * bhh[2 * E + e]);
  }
  if (GHC) {
    float* g = GHC + (size_t)w * K3;
    for (int n = tid; n < K3; n += 256) g[n] = bhh[n];
  }
}

// ---------- GHC split-K gemm: GHC[m,n] += H1C[m, kslice] . Whh[n, kslice] ----------
// grid (24, M/64, 2); GHC pre-initialized with bhh by k_h1c
__global__ __launch_bounds__(256) void k_ghcs(const float* __restrict__ H1C,
                                              const float* __restrict__ Whh,
                                              float* __restrict__ GHC) {
  __shared__ float As[16][64];
  __shared__ float Ws[16][64];
  int tid = threadIdx.x;
  int nBase = blockIdx.x * 64;
  int mBase = blockIdx.y * 64;
  int kbeg = blockIdx.z * 256;
  int tx = tid & 15, ty = tid >> 4;
  int li = tid & 63, lk = (tid >> 6) * 4;
  float acc[4][4] = {{0.f,0.f,0.f,0.f},{0.f,0.f,0.f,0.f},{0.f,0.f,0.f,0.f},{0.f,0.f,0.f,0.f}};
  const float* Arow = H1C + (size_t)(mBase + li) * E + kbeg;
  const float* Wrow = Whh + (size_t)(nBase + li) * E + kbeg;
  float4 av = *(const float4*)(Arow + lk);
  float4 wv = *(const float4*)(Wrow + lk);
  for (int k0 = 0; k0 < 256; k0 += 16) {
    As[lk + 0][li] = av.x; As[lk + 1][li] = av.y;
    As[lk + 2][li] = av.z; As[lk + 3][li] = av.w;
    Ws[lk + 0][li] = wv.x; Ws[lk + 1][li] = wv.y;
    Ws[lk + 2][li] = wv.z; Ws[lk + 3][li] = wv.w;
    __syncthreads();
    if (k0 + 16 < 256) {
      av = *(const float4*)(Arow + k0 + 16 + lk);
      wv = *(const float4*)(Wrow + k0 + 16 + lk);
    }
    TILE_FMA
    __syncthreads();
  }
#pragma unroll
  for (int r = 0; r < 4; ++r) {
    int mm = mBase + ty * 4 + r;
#pragma unroll
    for (int c = 0; c < 4; ++c) {
      int nn = nBase + tx * 4 + c;
      atomicAdd(&GHC[(size_t)mm * K3 + nn], acc[r][c]);
    }
  }
}

// ---------- pair + fc score (h1 from H1C) ----------
__global__ __launch_bounds__(256) void k_pairc(const int* __restrict__ wlb,
                                               const int* __restrict__ wlL,
                                               const int* __restrict__ wlR,
                                               const float* __restrict__ GI,
                                               const float* __restrict__ GHC,
                                               const float* __restrict__ H1C,
                                               const float* __restrict__ wfc,
                                               const float* __restrict__ bfc,
                                               float* __restrict__ PAIR,
                                               float* __restrict__ SCR) {
  __shared__ float sb[256];
  int w = blockIdx.x, tid = threadIdx.x;
  int b = wlb[w], ls = wlL[w], rs = wlR[w];
  const float* gr = GI + (size_t)(b * 16 + rs) * K3;
  const float* gh = GHC + (size_t)w * K3;
  const float* h = H1C + (size_t)w * E;
  float* p = PAIR + (size_t)(b * 16 + ls) * E;
  float part = 0.f;
  for (int e = tid; e < E; e += 256) {
    float r = sigm(gr[e] + gh[e]);
    float z = sigm(gr[E + e] + gh[E + e]);
    float n = tanhf(gr[2 * E + e] + r * gh[2 * E + e]);
    float pv = (1.f - z) * n + z * h[e];
    p[e] = pv;
    part += pv * wfc[e];
  }
  float d = brsum(part, sb);
  if (tid == 0) SCR[b * 16 + ls] = sigm(d + bfc[0]);
}

// ---------- fused sel + scores split-K gemm into pre-initialized SCT ----------
// grid (24, 2, 2). Block (0, y, 0) additionally writes pos/wl/xdst.
__global__ __launch_bounds__(256) void k_qscsel(const float* __restrict__ PAIR,
                                                const float* __restrict__ SCR,
                                                const int* __restrict__ pin,
                                                int* __restrict__ pout,
                                                int* __restrict__ wlb,
                                                int* __restrict__ wlL,
                                                int* __restrict__ wlR,
                                                int* __restrict__ xdst,
                                                const float* __restrict__ Gbig,
                                                float* __restrict__ SCT,
                                                int P, int finalMode) {
  __shared__ float As[16][64];
  __shared__ float Ws[16][64];
  __shared__ int sxd[64];
  int tid = threadIdx.x;
  int nBase = blockIdx.x * 64;
  int mBase = blockIdx.y * 64;
  int kbeg = blockIdx.z * 256;
  if (tid < 64) {
    int b = mBase + tid;
    if (finalMode) {
      int xr = b * 16 + pin[b * 16];
      sxd[tid] = xr;
      if (blockIdx.x == 0 && blockIdx.z == 0) xdst[b] = xr;
    } else {
      int L = P + 1;
      int lp[16];
      for (int i = 0; i < L; ++i) lp[i] = pin[b * 16 + i];
      float best = -1e30f; int sel = 0;
      for (int i = 0; i < P; ++i) {
        float v = SCR[b * 16 + lp[i]];
        if (v > best) { best = v; sel = i; }
      }
      int r1i = (sel + 2 < L) ? sel + 2 : L - 1;
      int l1 = lp[sel], r1 = lp[r1i];
      int l0 = (sel > 0) ? lp[sel - 1] : l1;
      int r0 = (sel > 0) ? lp[sel] : r1;
      sxd[tid] = b * 16 + l1;
      if (blockIdx.x == 0 && blockIdx.z == 0) {
        wlb[2 * b] = b;     wlL[2 * b] = l0;     wlR[2 * b] = r0;
        wlb[2 * b + 1] = b; wlL[2 * b + 1] = l1; wlR[2 * b + 1] = r1;
        xdst[b] = b * 16 + l1;
        for (int i = 0; i < L - 1; ++i)
          pout[b * 16 + i] = (i <= sel) ? lp[i] : lp[i + 1];
      }
    }
  }
  __syncthreads();
  int tx = tid & 15, ty = tid >> 4;
  int li = tid & 63, lk = (tid >> 6) * 4;
  float acc[4][4] = {{0.f,0.f,0.f,0.f},{0.f,0.f,0.f,0.f},{0.f,0.f,0.f,0.f},{0.f,0.f,0.f,0.f}};
  const float* Arow = PAIR + (size_t)sxd[li] * E + kbeg;
  int n = nBase + li;
  const float* Wrow = (n < 1512) ? (Gbig + (size_t)n * E + kbeg) : nullptr;
  float4 av = *(const float4*)(Arow + lk);
  float4 wv = Wrow ? *(const float4*)(Wrow + lk) : make_float4(0.f, 0.f, 0.f, 0.f);
  for (int k0 = 0; k0 < 256; k0 += 16) {
    As[lk + 0][li] = av.x; As[lk + 1][li] = av.y;
    As[lk + 2][li] = av.z; As[lk + 3][li] = av.w;
    Ws[lk + 0][li] = wv.x; Ws[lk + 1][li] = wv.y;
    Ws[lk + 2][li] = wv.z; Ws[lk + 3][li] = wv.w;
    __syncthreads();
    if (k0 + 16 < 256) {
      av = *(const float4*)(Arow + k0 + 16 + lk);
      wv = Wrow ? *(const float4*)(Wrow + k0 + 16 + lk) : make_float4(0.f, 0.f, 0.f, 0.f);
    }
    TILE_FMA
    __syncthreads();
  }
#pragma unroll
  for (int r = 0; r < 4; ++r) {
    int mm = mBase + ty * 4 + r;
#pragma unroll
    for (int c = 0; c < 4; ++c) {
      int nn = nBase + tx * 4 + c;
      if (nn < 1512) atomicAdd(&SCT[(size_t)mm * K3 + nn], acc[r][c]);
    }
  }
}

// ---------- softmax/entropy + A2 build + GI row init + SCT re-init ----------
__global__ __launch_bounds__(256) void k_sm(float* __restrict__ SCT,
                                            const float* __restrict__ PAIR,
                                            const int* __restrict__ xdst,
                                            const float* __restrict__ v12,
                                            const float* __restrict__ c0s,
                                            float* __restrict__ SC,
                                            float* __restrict__ A2,
                                            float* __restrict__ GI,
                                            const float* __restrict__ bih,
                                            const float* __restrict__ gb,
                                            float* __restrict__ LOSS,
                                            int t, int finalMode) {
  __shared__ float sb[256];
  __shared__ float sps[E];
  int b = blockIdx.x, tid = threadIdx.x;
  float* row = SCT + (size_t)b * K3;
  int xr = xdst[b];
  const float* sp = PAIR + (size_t)xr * E;
  for (int i = tid; i < E; i += 256) sps[i] = sp[i];
  __syncthreads();
  // bilinear self-score: raw Mqk part in cols 1000..1511
  float part = 0.f;
  for (int i = tid; i < E; i += 256) part += sps[i] * (row[1000 + i] + v12[i]);
  float last = (brsum(part, sb) + c0s[0]) * SCALE;
  float s[4];
  float ml = last;
#pragma unroll
  for (int q = 0; q < 4; ++q) {
    int j = tid + q * 256;
    s[q] = (j < 1000) ? row[j] * SCALE : -1e30f;  // row holds raw dot+gb
    ml = fmaxf(ml, s[q]);
  }
  float mx = brmax(ml, sb);
  float zp = 0.f, s1p = 0.f;
#pragma unroll
  for (int q = 0; q < 4; ++q) {
    int j = tid + q * 256;
    if (j < 1000) { float e = expf(s[q] - mx); zp += e; s1p += e * s[q]; }
  }
  if (tid == 0) { float e = expf(last - mx); zp += e; s1p += e * last; }
  float z = brsum(zp, sb);
  float s1 = brsum(s1p, sb);
  if (tid == 0) LOSS[b * 16 + t] = mx + logf(z) - s1 / z;
  if (!finalMode) {
    float inv = 1.f / z;
    float* a = A2 + (size_t)b * K3;
#pragma unroll
    for (int q = 0; q < 4; ++q) {
      int j = tid + q * 256;
      if (j < 1000) a[j] = expf(s[q] - mx) * inv;
    }
    if (tid < 24) a[1000 + tid] = 0.f;
    float pr = expf(last - mx) * inv;
    for (int i = tid; i < E; i += 256) a[1024 + i] = pr * sps[i];
    float* g = GI + (size_t)xr * K3;
    for (int n2 = tid; n2 < K3; n2 += 256) g[n2] = bih[n2];
    // re-init SCT row for the next step's split-K accumulation
    for (int n2 = tid; n2 < 1512; n2 += 256) row[n2] = (n2 < 1000) ? gb[n2] : 0.f;
  } else {
    float* so = SC + (size_t)b * (R + 1);
#pragma unroll
    for (int q = 0; q < 4; ++q) {
      int j = tid + q * 256;
      if (j < 1000) so[j] = s[q];
    }
    if (tid == 0) so[R] = last;
  }
}

// ---------- fused merged+GI gemm, split-K atomic (grid (24,2,4)) ----------
__global__ __launch_bounds__(256) void k_giup(const float* __restrict__ A2,
                                              const float* __restrict__ Wbig,
                                              float* __restrict__ GI,
                                              const int* __restrict__ xdst) {
  __shared__ float As[16][64];
  __shared__ float Ws[16][64];
  int tid = threadIdx.x;
  int nBase = blockIdx.x * 64;
  int mBase = blockIdx.y * 64;
  int kbeg = blockIdx.z * 384;
  int tx = tid & 15, ty = tid >> 4;
  int li = tid & 63, lk = (tid >> 6) * 4;
  int wr = tid >> 6;
  float acc[4][4] = {{0.f,0.f,0.f,0.f},{0.f,0.f,0.f,0.f},{0.f,0.f,0.f,0.f},{0.f,0.f,0.f,0.f}};
  const float* Arow = A2 + (size_t)(mBase + li) * K3;
  for (int k0 = kbeg; k0 < kbeg + 384; k0 += 16) {
    float4 av = *(const float4*)(Arow + k0 + lk);
    As[lk + 0][li] = av.x; As[lk + 1][li] = av.y;
    As[lk + 2][li] = av.z; As[lk + 3][li] = av.w;
#pragma unroll
    for (int j = 0; j < 4; ++j)
      Ws[wr * 4 + j][li] = Wbig[(size_t)(k0 + wr * 4 + j) * K3 + nBase + li];
    __syncthreads();
    TILE_FMA
    __syncthreads();
  }
#pragma unroll
  for (int r = 0; r < 4; ++r) {
    int mm = mBase + ty * 4 + r;
    size_t crow = (size_t)xdst[mm] * K3;
#pragma unroll
    for (int c = 0; c < 4; ++c) {
      int nn = nBase + tx * 4 + c;
      atomicAdd(&GI[crow + nn], acc[r][c]);
    }
  }
}

// ---------- final write ----------
__global__ __launch_bounds__(256) void k_writeout(const float* __restrict__ SC,
                                                  const float* __restrict__ LOSS,
                                                  float* __restrict__ out) {
  int idx = blockIdx.x * 256 + threadIdx.x;
  const int NS = B * (R + 1);
  if (idx < NS) {
    out[idx] = SC[idx];
  } else if (idx < NS + B * 16) {
    int r = idx - NS;
    int t = r & 15;
    out[idx] = (t == 14) ? 0.f : LOSS[r];
  }
}

extern "C" void kernel_launch(void* const* d_in, const int* in_sizes, int n_in,
                              void* d_out, int out_size, void* d_ws, size_t ws_size,
                              hipStream_t stream) {
  (void)in_sizes; (void)n_in; (void)out_size; (void)ws_size;
  const int* tokens = (const int*)d_in[0];
  const float* emb = (const float*)d_in[1];
  const float* W_ih = (const float*)d_in[2];
  const float* W_hh = (const float*)d_in[3];
  const float* b_ih = (const float*)d_in[4];
  const float* b_hh = (const float*)d_in[5];
  const float* w_fc = (const float*)d_in[6];
  const float* b_fc = (const float*)d_in[7];
  const float* Wq = (const float*)d_in[8];
  const float* bq = (const float*)d_in[9];
  const float* Wk = (const float*)d_in[10];
  const float* bk = (const float*)d_in[11];
  float* out = (float*)d_out;

  float* ws = (float*)d_ws;
  size_t o = 0;
  float* GI = ws + o;    o += (size_t)B * S * K3;
  float* GHC = ws + o;   o += (size_t)NW0 * K3;
  float* H1C = ws + o;   o += (size_t)NW0 * E;
  float* PAIR = ws + o;  o += (size_t)B * S * E;
  float* Wbig = ws + o;  o += (size_t)K3 * K3;       // [EW(1000) | 0(24) | W_ih^T(512)] k-major
  float* Gbig = ws + o;  o += (size_t)1512 * E;      // [G2(1000) ; Mqk(512)]
  float* KREL = ws + o;  o += (size_t)R * E;
  float* WqT = ws + o;   o += (size_t)E * E;
  float* WkT = ws + o;   o += (size_t)E * E;
  float* SCT = ws + o;   o += (size_t)B * K3;
  float* A2 = ws + o;    o += (size_t)B * K3;
  float* SC = ws + o;    o += (size_t)B * (R + 1);
  float* gb = ws + o;    o += 1024;
  float* v12 = ws + o;   o += 512;
  float* c0s = ws + o;   o += 16;
  float* LOSS = ws + o;  o += B * 16;
  float* SCR = ws + o;   o += B * 16;
  int* pos0 = (int*)(ws + o); o += B * 16;
  int* pos1 = (int*)(ws + o); o += B * 16;
  int* wlb = (int*)(ws + o);  o += NW0;
  int* wlL = (int*)(ws + o);  o += NW0;
  int* wlR = (int*)(ws + o);  o += NW0;
  int* xdst = (int*)(ws + o); o += B;

  // ---- setup ----
  k_initwl<<<8, 256, 0, stream>>>(pos0, wlb, wlL, wlR);
  k_tr<<<dim3(8, 8), 256, 0, stream>>>(Wq, E, WqT, E);
  k_tr<<<dim3(8, 8), 256, 0, stream>>>(Wk, E, WkT, E);
  k_tr<<<dim3(8, 24), 256, 0, stream>>>(W_ih, E, Wbig + (size_t)1024 * K3, K3);
  k_gemm<<<dim3(8, 16), 256, 0, stream>>>(emb, E, R, Wk, E, E, bk, 1.f, KREL, E);
  k_gemm<<<dim3(24, 16), 256, 0, stream>>>(emb, E, R, W_ih, K3, E, nullptr, 1.f, Wbig, K3);
  k_gemm<<<dim3(8, 16), 256, 0, stream>>>(KREL, E, R, WqT, E, E, nullptr, 1.f, Gbig, E);
  k_gemm<<<dim3(8, 8), 256, 0, stream>>>(WqT, E, E, WkT, E, E, nullptr, 1.f,
                                         Gbig + (size_t)1000 * E, E);
  k_misc<<<32, 256, 0, stream>>>(Wbig, WqT, WkT, bq, bk, KREL, v12, c0s, gb);
  k_giinit<<<B * S + 8, 256, 0, stream>>>(tokens, Wbig, b_ih, GI, gb, SCT);
  k_h1c<<<NW0, 256, 0, stream>>>(wlb, wlL, GI, b_hh, H1C, nullptr);
  k_gemm<<<dim3(24, 30), 256, 0, stream>>>(H1C, E, NW0, W_hh, K3, E, b_hh, 1.f, GHC, K3);
  k_pairc<<<NW0, 256, 0, stream>>>(wlb, wlL, wlR, GI, GHC, H1C, w_fc, b_fc, PAIR, SCR);

  // ---- 14 merge steps, 6 kernels each ----
  for (int t = 0; t < 14; ++t) {
    int* pin = (t & 1) ? pos1 : pos0;
    int* pout = (t & 1) ? pos0 : pos1;
    k_qscsel<<<dim3(24, 2, 2), 256, 0, stream>>>(PAIR, SCR, pin, pout, wlb, wlL, wlR,
                                                 xdst, Gbig, SCT, 15 - t, 0);
    k_sm<<<B, 256, 0, stream>>>(SCT, PAIR, xdst, v12, c0s, SC, A2, GI, b_ih, gb,
                                LOSS, t, 0);
    k_giup<<<dim3(24, 2, 4), 256, 0, stream>>>(A2, Wbig, GI, xdst);
    k_h1c<<<NWS, 256, 0, stream>>>(wlb, wlL, GI, b_hh, H1C, GHC);
    k_ghcs<<<dim3(24, 4, 2), 256, 0, stream>>>(H1C, W_hh, GHC);
    k_pairc<<<NWS, 256, 0, stream>>>(wlb, wlL, wlR, GI, GHC, H1C, w_fc, b_fc, PAIR, SCR);
  }

  // ---- final: h2 = PAIR[b][pos0[b*16]]; attention + loss col 15 ----
  k_qscsel<<<dim3(24, 2, 2), 256, 0, stream>>>(PAIR, SCR, pos0, pos1, wlb, wlL, wlR,
                                               xdst, Gbig, SCT, 1, 1);
  k_sm<<<B, 256, 0, stream>>>(SCT, PAIR, xdst, v12, c0s, SC, A2, GI, b_ih, gb,
                              LOSS, 15, 1);
  k_writeout<<<(B * (R + 1) + B * 16 + 255) / 256, 256, 0, stream>>>(SC, LOSS, out);
}